// Round 3
// baseline (1846.452 us; speedup 1.0000x reference)
//
#include <hip/hip_runtime.h>
#include <hip/hip_bf16.h>
#include <math.h>

using bf16 = __hip_bfloat16;
typedef short v8s __attribute__((ext_vector_type(8)));
typedef float v4f __attribute__((ext_vector_type(4)));

#define B_ 2
#define S_ 2048
#define DIM_ 2048
#define H_ 16
#define QL_ 1536
#define KVL_ 512
#define NOPE_ 128
#define ROPE_ 64
#define QKH_ 192
#define DQK_ 576
#define LOG2E 1.4426950408889634f
#define SCALE_ 0.07216878364870323f   // 192^-0.5

__device__ __forceinline__ float bf2f(bf16 x){ return __bfloat162float(x); }
__device__ __forceinline__ bf16 f2bf(float x){ return __float2bfloat16(x); }
union bfu { bf16 b; short s; };
__device__ __forceinline__ short f2s(float x){ bfu u; u.b = __float2bfloat16(x); return u.s; }
__device__ __forceinline__ v4f mfma16(v8s a, v8s b, v4f c){
    return __builtin_amdgcn_mfma_f32_16x16x32_bf16(a, b, c, 0, 0, 0);
}
__device__ __forceinline__ v4f vzero(){ v4f z = {0.f,0.f,0.f,0.f}; return z; }

// load 8 contiguous elems as bf16 fragment; f32 -> convert (RNE; exact if values are bf16-rounded)
__device__ __forceinline__ v8s ld8(const void* base, long e, bool f32){
    if (f32){
        const float4* p = reinterpret_cast<const float4*>((const float*)base + e);
        float4 a = p[0], b = p[1];
        v8s r;
        r[0]=f2s(a.x); r[1]=f2s(a.y); r[2]=f2s(a.z); r[3]=f2s(a.w);
        r[4]=f2s(b.x); r[5]=f2s(b.y); r[6]=f2s(b.z); r[7]=f2s(b.w);
        return r;
    }
    return *reinterpret_cast<const v8s*>((const bf16*)base + e);
}
__device__ __forceinline__ float ld1(const void* base, long e, bool f32){
    return f32 ? ((const float*)base)[e] : bf2f(((const bf16*)base)[e]);
}

// ---------------- dtype probe: freqs_cos[0] == 1.0 exactly ----------------
__global__ void detect_k(const unsigned* fc, int* flag){
    if (threadIdx.x == 0 && blockIdx.x == 0)
        *flag = (*fc == 0x3f800000u) ? 0 : 1;   // 0 = fp32 buffers, 1 = bf16 buffers
}

// ---------------- generic GEMM: C = A @ Bt^T (row-major; Bt is (N,K)) ----------------
// aExt/bExt/cExt: operand lives in an external buffer (dtype per *gf); else internal bf16.
__global__ __launch_bounds__(256) void gemm_bt(
    const void* __restrict__ A, long lda, long strideA, int aExt,
    const void* __restrict__ Bt, long ldb, long strideB, int bExt,
    void* __restrict__ C, long ldc, long strideC, int cExt,
    int K, const int* __restrict__ gf)
{
    const bool f32 = (*gf == 0);
    const bool a32 = aExt && f32, b32 = bExt && f32, c32 = cExt && f32;
    __shared__ bf16 As[64][40];
    __shared__ bf16 Bs[64][40];
    const int tid = threadIdx.x;
    const int w = tid >> 6, lane = tid & 63, quad = lane >> 4, l15 = lane & 15;
    const long aoff = (long)blockIdx.z * strideA;
    const long boff = (long)blockIdx.z * strideB;
    const long coff = (long)blockIdx.z * strideC;
    const int m0 = blockIdx.y * 64, n0 = blockIdx.x * 64;
    const int lr = tid >> 2, lc = (tid & 3) * 8;

    v4f acc[4];
    #pragma unroll
    for (int i = 0; i < 4; ++i) acc[i] = vzero();

    for (int k0 = 0; k0 < K; k0 += 32) {
        v8s av = ld8(A, aoff + (long)(m0 + lr) * lda + k0 + lc, a32);
        v8s bv = ld8(Bt, boff + (long)(n0 + lr) * ldb + k0 + lc, b32);
        __syncthreads();
        *reinterpret_cast<v8s*>(&As[lr][lc]) = av;
        *reinterpret_cast<v8s*>(&Bs[lr][lc]) = bv;
        __syncthreads();
        v8s af = *reinterpret_cast<const v8s*>(&As[w * 16 + l15][quad * 8]);
        #pragma unroll
        for (int nt = 0; nt < 4; ++nt) {
            v8s bfv = *reinterpret_cast<const v8s*>(&Bs[nt * 16 + l15][quad * 8]);
            acc[nt] = mfma16(af, bfv, acc[nt]);
        }
    }
    #pragma unroll
    for (int nt = 0; nt < 4; ++nt)
        #pragma unroll
        for (int r = 0; r < 4; ++r) {
            long off = coff + (long)(m0 + w * 16 + quad * 4 + r) * ldc + n0 + nt * 16 + l15;
            if (c32) ((float*)C)[off] = acc[nt][r];
            else     ((bf16*)C)[off] = f2bf(acc[nt][r]);
        }
}

// ---------------- RMSNorm width 1536, in-place safe (internal bf16; wt external) ----
__global__ __launch_bounds__(256) void rmsnorm_q(
    const bf16* __restrict__ in, const void* __restrict__ wt, bf16* __restrict__ out,
    const int* __restrict__ gf)
{
    const bool f32 = (*gf == 0);
    int row = blockIdx.x;
    const bf16* x = in + (long)row * QL_;
    float v[6]; float ss = 0.f;
    #pragma unroll
    for (int i = 0; i < 6; ++i) { v[i] = bf2f(x[threadIdx.x + i * 256]); ss += v[i] * v[i]; }
    #pragma unroll
    for (int off = 1; off < 64; off <<= 1) ss += __shfl_xor(ss, off);
    __shared__ float ws4[4];
    if ((threadIdx.x & 63) == 0) ws4[threadIdx.x >> 6] = ss;
    __syncthreads();
    float rs = rsqrtf((ws4[0] + ws4[1] + ws4[2] + ws4[3]) / (float)QL_ + 1e-6f);
    bf16* o = out + (long)row * QL_;
    #pragma unroll
    for (int i = 0; i < 6; ++i) {
        int c = threadIdx.x + i * 256;
        o[c] = f2bf(v[i] * rs * ld1(wt, c, f32));
    }
}

// ---------------- kv: rmsnorm(512) + rope(64), in-place safe ----------------
__global__ __launch_bounds__(256) void kv_proc(
    bf16* __restrict__ kvf, const void* __restrict__ wt,
    const void* __restrict__ fcos, const void* __restrict__ fsin,
    const int* __restrict__ gf)
{
    const bool f32 = (*gf == 0);
    int row = blockIdx.x;             // b*2048 + s
    int s = row & (S_ - 1);
    bf16* x = kvf + (long)row * DQK_;
    float v[2]; float ss = 0.f;
    #pragma unroll
    for (int i = 0; i < 2; ++i) { v[i] = bf2f(x[threadIdx.x + i * 256]); ss += v[i] * v[i]; }
    #pragma unroll
    for (int off = 1; off < 64; off <<= 1) ss += __shfl_xor(ss, off);
    __shared__ float ws4[4];
    if ((threadIdx.x & 63) == 0) ws4[threadIdx.x >> 6] = ss;
    __syncthreads();
    float rs = rsqrtf((ws4[0] + ws4[1] + ws4[2] + ws4[3]) / (float)KVL_ + 1e-6f);
    #pragma unroll
    for (int i = 0; i < 2; ++i) {
        int c = threadIdx.x + i * 256;
        x[c] = f2bf(v[i] * rs * ld1(wt, c, f32));
    }
    if (threadIdx.x < 32) {
        int i = threadIdx.x;
        float x0 = bf2f(x[KVL_ + 2 * i]), x1 = bf2f(x[KVL_ + 2 * i + 1]);
        float c = ld1(fcos, s * 32 + i, f32), sn = ld1(fsin, s * 32 + i, f32);
        x[KVL_ + 2 * i]     = f2bf(x0 * c - x1 * sn);
        x[KVL_ + 2 * i + 1] = f2bf(x0 * sn + x1 * c);
    }
}

// ---------------- q pack: qfull (4096,3072) -> qnope (H,4096,128) + roped qpe (H*B,S,64) ----
__global__ __launch_bounds__(512) void q_pack(
    const bf16* __restrict__ qfull, const void* __restrict__ fcos, const void* __restrict__ fsin,
    bf16* __restrict__ qnope, bf16* __restrict__ qpe, const int* __restrict__ gf)
{
    const bool f32 = (*gf == 0);
    int row = blockIdx.x;             // b*2048 + s
    int s = row & (S_ - 1);
    int b = row >> 11;
    const bf16* q = qfull + (long)row * (H_ * QKH_);
    int t = threadIdx.x;
    {   // rope: h = t>>5, i = t&31
        int h = t >> 5, i = t & 31;
        float x0 = bf2f(q[h * QKH_ + NOPE_ + 2 * i]);
        float x1 = bf2f(q[h * QKH_ + NOPE_ + 2 * i + 1]);
        float c = ld1(fcos, s * 32 + i, f32), sn = ld1(fsin, s * 32 + i, f32);
        bf16* dst = qpe + ((long)(h * B_ + b) * S_ + s) * ROPE_;
        dst[2 * i]     = f2bf(x0 * c - x1 * sn);
        dst[2 * i + 1] = f2bf(x0 * sn + x1 * c);
    }
    if (t < 256) {  // nope copy
        int h = t >> 4, d0 = (t & 15) * 8;
        v8s v = *reinterpret_cast<const v8s*>(q + h * QKH_ + d0);
        *reinterpret_cast<v8s*>(qnope + ((long)h * 4096 + row) * NOPE_ + d0) = v;
    }
}

// ---------------- V transpose: kvf[:, :512] -> Vt (B, 512, S) ----------------
__global__ __launch_bounds__(256) void v_transpose(
    const bf16* __restrict__ kcomb, bf16* __restrict__ vt)
{
    __shared__ bf16 tile[64][72];
    int b = blockIdx.z, t0 = blockIdx.x * 64, c0 = blockIdx.y * 64;
    int tid = threadIdx.x;
    int r = tid >> 2, sg = tid & 3;
    const bf16* src = kcomb + ((long)b * S_ + t0 + r) * DQK_ + c0 + sg * 16;
    #pragma unroll
    for (int i = 0; i < 2; ++i)
        *reinterpret_cast<v8s*>(&tile[r][sg * 16 + i * 8]) = reinterpret_cast<const v8s*>(src)[i];
    __syncthreads();
    int c = tid >> 2;
    bf16* dst = vt + ((long)b * KVL_ + c0 + c) * S_ + t0 + sg * 16;
    bf16 tmp[16];
    #pragma unroll
    for (int i = 0; i < 16; ++i) tmp[i] = tile[sg * 16 + i][c];
    #pragma unroll
    for (int i = 0; i < 2; ++i)
        reinterpret_cast<v8s*>(dst)[i] = *reinterpret_cast<v8s*>(&tmp[i * 8]);
}

// ---------------- wkv_b nope rows transpose: (H,128,512) -> wkvbt (H,512,128) ----------------
__global__ __launch_bounds__(256) void wkvb_t_kernel(
    const void* __restrict__ wkvb, bf16* __restrict__ outp, const int* __restrict__ gf)
{
    const bool f32 = (*gf == 0);
    long idx = (long)blockIdx.x * 256 + threadIdx.x;  // 16*512*128
    int h = (int)(idx >> 16);
    int rem = (int)(idx & 65535);
    int c = rem >> 7, d = rem & 127;
    outp[idx] = f2bf(ld1(wkvb, ((long)(h * 256 + d)) * KVL_ + c, f32));
}

// ---------------- flash attention + on-the-fly q_abs + fused output projection ----------------
// Per block: 64 q-rows, one (h,b). Prologue computes qreg = [qnope@wkvbt_h^T | qpe] (A-frag),
// main loop: QK^T(576) -> online softmax -> PV(512), epilogue: out_h = (o/l) @ wv_h^T.
// LDS (bf16 elems, total 26112 = 52.2 KB):
//   prologue: Qs @0 (64x136), Qn @8704 (64x136), Wt @17408 (64x136)
//   main:     KVc @0 (64x72 K / 128x72 V = 9216), Ps @9216 (4 x 16x72)
//   epilogue: Po @0 (64x264=16896), Wvs @16896 (128x40=5120)
__global__ __launch_bounds__(256, 1) void attn(
    const bf16* __restrict__ qnope, // (H, 4096, 128)
    const bf16* __restrict__ qpe,   // (H*B, S, 64)
    const bf16* __restrict__ kc,    // (B, S, 576)
    const bf16* __restrict__ vt,    // (B, 512, S)
    const bf16* __restrict__ wkvbt, // (H, 512, 128)
    const void* __restrict__ wkvb,  // external (H*256, 512); rows h*256+128.. = wv
    bf16* __restrict__ oheads,      // (4096, 2048), head h at cols h*128..
    const int* __restrict__ gf)
{
    __shared__ bf16 sm[26112];
    const bool e32 = (*gf == 0);
    const int tid = threadIdx.x;
    const int w = tid >> 6, lane = tid & 63, quad = lane >> 4, l15 = lane & 15;
    const int qb = gridDim.x - 1 - blockIdx.x;   // longest blocks first
    const int bh = blockIdx.y;                    // h*B + b
    const int b = bh & (B_ - 1), h = bh >> 1;
    const int q0 = qb * 64;

    // ---- prologue: stage qnope tile once
    {
        #pragma unroll
        for (int i = 0; i < 4; ++i) {
            int a = tid + i * 256, rr = a >> 4, sg = a & 15;
            *reinterpret_cast<v8s*>(&sm[8704 + rr * 136 + sg * 8]) =
                *reinterpret_cast<const v8s*>(qnope + ((long)h * 4096 + b * 2048 + q0 + rr) * NOPE_ + sg * 8);
        }
    }
    v8s qreg[18];
    // 4 passes x 128 cols of q_abs = qnope_tile @ wkvbt_h^T
    for (int p = 0; p < 4; ++p) {
        for (int nb = 0; nb < 2; ++nb) {
            __syncthreads();
            #pragma unroll
            for (int i = 0; i < 4; ++i) {   // stage Wt: 64 rows (c-dim) x 128 (d-dim)
                int a = tid + i * 256, rr = a >> 4, sg = a & 15;
                *reinterpret_cast<v8s*>(&sm[17408 + rr * 136 + sg * 8]) =
                    *reinterpret_cast<const v8s*>(wkvbt + ((long)h * 512 + p * 128 + nb * 64 + rr) * NOPE_ + sg * 8);
            }
            __syncthreads();
            v4f qacc[4];
            #pragma unroll
            for (int i = 0; i < 4; ++i) qacc[i] = vzero();
            #pragma unroll
            for (int kk = 0; kk < 4; ++kk) {
                v8s aq = *reinterpret_cast<const v8s*>(&sm[8704 + (w * 16 + l15) * 136 + kk * 32 + quad * 8]);
                #pragma unroll
                for (int nt = 0; nt < 4; ++nt) {
                    v8s bw = *reinterpret_cast<const v8s*>(&sm[17408 + (nt * 16 + l15) * 136 + kk * 32 + quad * 8]);
                    qacc[nt] = mfma16(aq, bw, qacc[nt]);
                }
            }
            #pragma unroll
            for (int nt = 0; nt < 4; ++nt)
                #pragma unroll
                for (int r = 0; r < 4; ++r)
                    sm[(w * 16 + quad * 4 + r) * 136 + nb * 64 + nt * 16 + l15] = f2bf(qacc[nt][r]);
        }
        // extract this pass's A-fragments (wave-private rows; same-wave LDS ordering)
        #pragma unroll
        for (int c2 = 0; c2 < 2; ++c2)
            #pragma unroll
            for (int ks = 0; ks < 2; ++ks)
                qreg[p * 4 + c2 * 2 + ks] =
                    *reinterpret_cast<const v8s*>(&sm[(w * 16 + l15) * 136 + c2 * 64 + ks * 32 + quad * 8]);
    }
    {   // qpe fragments
        const bf16* qp = qpe + ((long)bh * S_ + q0 + w * 16 + l15) * ROPE_;
        qreg[16] = *reinterpret_cast<const v8s*>(qp + quad * 8);
        qreg[17] = *reinterpret_cast<const v8s*>(qp + 32 + quad * 8);
    }

    const bf16* Kb = kc + (long)b * S_ * DQK_;
    const bf16* Vb = vt + (long)b * KVL_ * S_;
    bf16* KVc = sm;
    bf16* Ps  = sm + 9216 + w * 1152;

    float m_run[4], l_run[4];
    v4f o[32];
    #pragma unroll
    for (int i = 0; i < 32; ++i) o[i] = vzero();
    #pragma unroll
    for (int r = 0; r < 4; ++r) { m_run[r] = -3e38f; l_run[r] = 0.f; }

    for (int kb = 0; kb <= qb; ++kb) {
        const int t0 = kb * 64;
        v4f sacc[4];
        #pragma unroll
        for (int i = 0; i < 4; ++i) sacc[i] = vzero();

        // ---- scores: 9 chunks of 64 d-cols
        for (int c = 0; c < 9; ++c) {
            __syncthreads();
            #pragma unroll
            for (int i = 0; i < 2; ++i) {
                int a = tid + i * 256, rr = a >> 3, sg = a & 7;
                *reinterpret_cast<v8s*>(KVc + rr * 72 + sg * 8) =
                    *reinterpret_cast<const v8s*>(Kb + (long)(t0 + rr) * DQK_ + c * 64 + sg * 8);
            }
            __syncthreads();
            #pragma unroll
            for (int ks = 0; ks < 2; ++ks) {
                v8s aq = qreg[c * 2 + ks];
                #pragma unroll
                for (int nt = 0; nt < 4; ++nt) {
                    v8s bk = *reinterpret_cast<const v8s*>(KVc + (nt * 16 + l15) * 72 + ks * 32 + quad * 8);
                    sacc[nt] = mfma16(aq, bk, sacc[nt]);
                }
            }
        }

        // ---- scale + causal mask
        #pragma unroll
        for (int nt = 0; nt < 4; ++nt) {
            int col = t0 + nt * 16 + l15;
            #pragma unroll
            for (int r = 0; r < 4; ++r) {
                int row = q0 + w * 16 + quad * 4 + r;
                float s = sacc[nt][r] * SCALE_;
                sacc[nt][r] = (col <= row) ? s : -3e38f;
            }
        }
        // ---- online softmax (state replicated across each quad's 16 lanes)
        float al[4];
        #pragma unroll
        for (int r = 0; r < 4; ++r) {
            float mx = fmaxf(fmaxf(sacc[0][r], sacc[1][r]), fmaxf(sacc[2][r], sacc[3][r]));
            mx = fmaxf(mx, __shfl_xor(mx, 1));
            mx = fmaxf(mx, __shfl_xor(mx, 2));
            mx = fmaxf(mx, __shfl_xor(mx, 4));
            mx = fmaxf(mx, __shfl_xor(mx, 8));
            float mnew = fmaxf(m_run[r], mx);
            al[r] = exp2f((m_run[r] - mnew) * LOG2E);
            m_run[r] = mnew;
        }
        float rsum[4] = {0.f, 0.f, 0.f, 0.f};
        #pragma unroll
        for (int nt = 0; nt < 4; ++nt)
            #pragma unroll
            for (int r = 0; r < 4; ++r) {
                float pv = exp2f((sacc[nt][r] - m_run[r]) * LOG2E);
                rsum[r] += pv;
                Ps[(quad * 4 + r) * 72 + nt * 16 + l15] = f2bf(pv);
            }
        #pragma unroll
        for (int r = 0; r < 4; ++r) {
            float t = rsum[r];
            t += __shfl_xor(t, 1);
            t += __shfl_xor(t, 2);
            t += __shfl_xor(t, 4);
            t += __shfl_xor(t, 8);
            l_run[r] = l_run[r] * al[r] + t;
        }
        #pragma unroll
        for (int i = 0; i < 32; ++i)
            #pragma unroll
            for (int r = 0; r < 4; ++r) o[i][r] *= al[r];

        // ---- PV: 4 chunks of 128 V-rows (ctx cols)
        for (int vc = 0; vc < 4; ++vc) {
            __syncthreads();
            #pragma unroll
            for (int i = 0; i < 4; ++i) {
                int a = tid + i * 256, rr = a >> 3, sg = a & 7;
                *reinterpret_cast<v8s*>(KVc + rr * 72 + sg * 8) =
                    *reinterpret_cast<const v8s*>(Vb + (long)(vc * 128 + rr) * S_ + t0 + sg * 8);
            }
            __syncthreads();
            #pragma unroll
            for (int ks = 0; ks < 2; ++ks) {
                v8s pa = *reinterpret_cast<const v8s*>(Ps + l15 * 72 + ks * 32 + quad * 8);
                #pragma unroll
                for (int nt = 0; nt < 8; ++nt) {
                    v8s bv = *reinterpret_cast<const v8s*>(KVc + (nt * 16 + l15) * 72 + ks * 32 + quad * 8);
                    o[vc * 8 + nt] = mfma16(pa, bv, o[vc * 8 + nt]);
                }
            }
        }
    }

    // ---- fused epilogue: out_h = (o/l) @ wv_h^T, K=512 in 2x8 chunks
    __syncthreads();
    float inv[4];
    #pragma unroll
    for (int r = 0; r < 4; ++r) inv[r] = 1.0f / l_run[r];
    bf16* Po  = sm;            // [64][264], wave w owns rows w*16..+15
    bf16* Wvs = sm + 16896;    // [128][40]
    v4f oacc[8];
    #pragma unroll
    for (int i = 0; i < 8; ++i) oacc[i] = vzero();

    for (int Hh = 0; Hh < 2; ++Hh) {
        #pragma unroll
        for (int i = 0; i < 16; ++i) {
            int ii = Hh * 16 + i;
            #pragma unroll
            for (int r = 0; r < 4; ++r)
                Po[(w * 16 + quad * 4 + r) * 264 + i * 16 + l15] = f2bf(o[ii][r] * inv[r]);
        }
        for (int kcc = 0; kcc < 8; ++kcc) {
            __syncthreads();
            #pragma unroll
            for (int i = 0; i < 2; ++i) {
                int a = tid + i * 256, rr = a >> 2, sg = a & 3;
                *reinterpret_cast<v8s*>(Wvs + rr * 40 + sg * 8) =
                    ld8(wkvb, (long)(h * 256 + 128 + rr) * KVL_ + Hh * 256 + kcc * 32 + sg * 8, e32);
            }
            __syncthreads();
            v8s aq = *reinterpret_cast<const v8s*>(Po + (w * 16 + l15) * 264 + kcc * 32 + quad * 8);
            #pragma unroll
            for (int nt = 0; nt < 8; ++nt) {
                v8s bw = *reinterpret_cast<const v8s*>(Wvs + (nt * 16 + l15) * 40 + quad * 8);
                oacc[nt] = mfma16(aq, bw, oacc[nt]);
            }
        }
    }
    #pragma unroll
    for (int nt = 0; nt < 8; ++nt)
        #pragma unroll
        for (int r = 0; r < 4; ++r)
            oheads[(long)(b * S_ + q0 + w * 16 + quad * 4 + r) * 2048 + h * 128 + nt * 16 + l15] = f2bf(oacc[nt][r]);
}

extern "C" void kernel_launch(void* const* d_in, const int* in_sizes, int n_in,
                              void* d_out, int out_size, void* d_ws, size_t ws_size,
                              hipStream_t stream) {
    const void* x     = d_in[0];
    const void* fcos  = d_in[1];
    const void* fsin  = d_in[2];
    // d_in[3] = mask (causal) — implemented directly
    const void* wq_a  = d_in[4];
    const void* q_ln  = d_in[5];
    const void* wq_b  = d_in[6];
    const void* wkv_a = d_in[7];
    const void* kv_ln = d_in[8];
    const void* wkv_b = d_in[9];
    const void* wo    = d_in[10];

    // workspace (bf16 elems), peak 30,670,864 elems ~= 58.5 MiB
    bf16* W = (bf16*)d_ws;
    bf16* t0     = W;                 // 6,291,456 (dead after GEMM2)
    bf16* qnope  = W;                 // 8,388,608 (written by q_pack, after t0 dead)
    bf16* qpe    = W + 8388608L;      // 4,194,304
    bf16* qfull  = W + 12582912L;     // 12,582,912 (dead after q_pack)
    bf16* oheads = W + 12582912L;     // 8,388,608 (over qfull)
    bf16* kvf    = W + 25165824L;     // 2,359,296
    bf16* vtb    = W + 27525120L;     // 2,097,152
    bf16* wkvbt  = W + 29622272L;     // 1,048,576
    int*  gflag  = (int*)(W + 30670848L);

    detect_k<<<dim3(1), dim3(64), 0, stream>>>((const unsigned*)fcos, gflag);
    wkvb_t_kernel<<<dim3(4096), dim3(256), 0, stream>>>(wkv_b, wkvbt, gflag);

    // GEMM1: t0 = x @ wq_a^T   (4096 x 1536 x 2048)
    gemm_bt<<<dim3(24, 64, 1), dim3(256), 0, stream>>>(
        x, 2048L, 0L, 1, wq_a, 2048L, 0L, 1, t0, 1536L, 0L, 0, 2048, gflag);
    rmsnorm_q<<<dim3(4096), dim3(256), 0, stream>>>(t0, q_ln, t0, gflag);

    // GEMM2: qfull = t0 @ wq_b^T  (4096 x 3072 x 1536)
    gemm_bt<<<dim3(48, 64, 1), dim3(256), 0, stream>>>(
        t0, 1536L, 0L, 0, wq_b, 1536L, 0L, 1, qfull, 3072L, 0L, 0, 1536, gflag);

    // GEMM3: kvf = x @ wkv_a^T  (4096 x 576 x 2048)
    gemm_bt<<<dim3(9, 64, 1), dim3(256), 0, stream>>>(
        x, 2048L, 0L, 1, wkv_a, 2048L, 0L, 1, kvf, 576L, 0L, 0, 2048, gflag);

    q_pack<<<dim3(4096), dim3(512), 0, stream>>>(qfull, fcos, fsin, qnope, qpe, gflag);
    kv_proc<<<dim3(4096), dim3(256), 0, stream>>>(kvf, kv_ln, fcos, fsin, gflag);
    v_transpose<<<dim3(32, 8, 2), dim3(256), 0, stream>>>(kvf, vtb);

    // attention (+ on-the-fly q_abs, + fused per-head out projection) -> oheads
    attn<<<dim3(32, 32), dim3(256), 0, stream>>>(
        qnope, qpe, kvf, vtb, wkvbt, wkv_b, oheads, gflag);

    // GEMM7: out = oheads @ wo^T  (4096 x 2048 x 2048), out dtype per flag
    gemm_bt<<<dim3(32, 64, 1), dim3(256), 0, stream>>>(
        oheads, 2048L, 0L, 0, wo, 2048L, 0L, 1, d_out, 2048L, 0L, 1, 2048, gflag);
}

// Round 4
// 1379.725 us; speedup vs baseline: 1.3383x; 1.3383x over previous
//
#include <hip/hip_runtime.h>
#include <hip/hip_bf16.h>
#include <math.h>

using bf16 = __hip_bfloat16;
typedef short v8s __attribute__((ext_vector_type(8)));
typedef float v4f __attribute__((ext_vector_type(4)));

#define B_ 2
#define S_ 2048
#define DIM_ 2048
#define H_ 16
#define QL_ 1536
#define KVL_ 512
#define NOPE_ 128
#define ROPE_ 64
#define QKH_ 192
#define DQK_ 576
#define LOG2E 1.4426950408889634f
#define SCALE_ 0.07216878364870323f   // 192^-0.5

__device__ __forceinline__ float bf2f(bf16 x){ return __bfloat162float(x); }
__device__ __forceinline__ bf16 f2bf(float x){ return __float2bfloat16(x); }
union bfu { bf16 b; short s; };
__device__ __forceinline__ short f2s(float x){ bfu u; u.b = __float2bfloat16(x); return u.s; }
__device__ __forceinline__ v4f mfma16(v8s a, v8s b, v4f c){
    return __builtin_amdgcn_mfma_f32_16x16x32_bf16(a, b, c, 0, 0, 0);
}
__device__ __forceinline__ v4f vzero(){ v4f z = {0.f,0.f,0.f,0.f}; return z; }

// load 8 contiguous elems as bf16 fragment; f32 -> convert (RNE; exact if values are bf16-rounded)
__device__ __forceinline__ v8s ld8(const void* base, long e, bool f32){
    if (f32){
        const float4* p = reinterpret_cast<const float4*>((const float*)base + e);
        float4 a = p[0], b = p[1];
        v8s r;
        r[0]=f2s(a.x); r[1]=f2s(a.y); r[2]=f2s(a.z); r[3]=f2s(a.w);
        r[4]=f2s(b.x); r[5]=f2s(b.y); r[6]=f2s(b.z); r[7]=f2s(b.w);
        return r;
    }
    return *reinterpret_cast<const v8s*>((const bf16*)base + e);
}
__device__ __forceinline__ float ld1(const void* base, long e, bool f32){
    return f32 ? ((const float*)base)[e] : bf2f(((const bf16*)base)[e]);
}

// ---------------- dtype probe: freqs_cos[0] == 1.0 exactly ----------------
__global__ void detect_k(const unsigned* fc, int* flag){
    if (threadIdx.x == 0 && blockIdx.x == 0)
        *flag = (*fc == 0x3f800000u) ? 0 : 1;   // 0 = fp32 buffers, 1 = bf16 buffers
}

// ---------------- generic GEMM: C = A @ Bt^T (row-major; Bt is (N,K)) ----------------
// Ping-pong LDS double-buffer + register prefetch: 1 barrier per 32-K step.
__global__ __launch_bounds__(256) void gemm_bt(
    const void* __restrict__ A, long lda, long strideA, int aExt,
    const void* __restrict__ Bt, long ldb, long strideB, int bExt,
    void* __restrict__ C, long ldc, long strideC, int cExt,
    int K, const int* __restrict__ gf)
{
    const bool f32 = (*gf == 0);
    const bool a32 = aExt && f32, b32 = bExt && f32, c32 = cExt && f32;
    __shared__ bf16 As[2][64][40];
    __shared__ bf16 Bs[2][64][40];
    const int tid = threadIdx.x;
    const int w = tid >> 6, lane = tid & 63, quad = lane >> 4, l15 = lane & 15;
    const long aoff = (long)blockIdx.z * strideA;
    const long boff = (long)blockIdx.z * strideB;
    const long coff = (long)blockIdx.z * strideC;
    const int m0 = blockIdx.y * 64, n0 = blockIdx.x * 64;
    const int lr = tid >> 2, lc = (tid & 3) * 8;

    v4f acc[4];
    #pragma unroll
    for (int i = 0; i < 4; ++i) acc[i] = vzero();

    v8s av = ld8(A,  aoff + (long)(m0 + lr) * lda + lc, a32);
    v8s bv = ld8(Bt, boff + (long)(n0 + lr) * ldb + lc, b32);

    for (int k0 = 0; k0 < K; k0 += 32) {
        const int bi = (k0 >> 5) & 1;
        *reinterpret_cast<v8s*>(&As[bi][lr][lc]) = av;
        *reinterpret_cast<v8s*>(&Bs[bi][lr][lc]) = bv;
        if (k0 + 32 < K) {
            av = ld8(A,  aoff + (long)(m0 + lr) * lda + k0 + 32 + lc, a32);
            bv = ld8(Bt, boff + (long)(n0 + lr) * ldb + k0 + 32 + lc, b32);
        }
        __syncthreads();
        v8s af = *reinterpret_cast<const v8s*>(&As[bi][w * 16 + l15][quad * 8]);
        #pragma unroll
        for (int nt = 0; nt < 4; ++nt) {
            v8s bfv = *reinterpret_cast<const v8s*>(&Bs[bi][nt * 16 + l15][quad * 8]);
            acc[nt] = mfma16(af, bfv, acc[nt]);
        }
    }
    #pragma unroll
    for (int nt = 0; nt < 4; ++nt)
        #pragma unroll
        for (int r = 0; r < 4; ++r) {
            long off = coff + (long)(m0 + w * 16 + quad * 4 + r) * ldc + n0 + nt * 16 + l15;
            if (c32) ((float*)C)[off] = acc[nt][r];
            else     ((bf16*)C)[off] = f2bf(acc[nt][r]);
        }
}

// ---------------- RMSNorm width 1536, in-place safe (internal bf16; wt external) ----
__global__ __launch_bounds__(256) void rmsnorm_q(
    const bf16* __restrict__ in, const void* __restrict__ wt, bf16* __restrict__ out,
    const int* __restrict__ gf)
{
    const bool f32 = (*gf == 0);
    int row = blockIdx.x;
    const bf16* x = in + (long)row * QL_;
    float v[6]; float ss = 0.f;
    #pragma unroll
    for (int i = 0; i < 6; ++i) { v[i] = bf2f(x[threadIdx.x + i * 256]); ss += v[i] * v[i]; }
    #pragma unroll
    for (int off = 1; off < 64; off <<= 1) ss += __shfl_xor(ss, off);
    __shared__ float ws4[4];
    if ((threadIdx.x & 63) == 0) ws4[threadIdx.x >> 6] = ss;
    __syncthreads();
    float rs = rsqrtf((ws4[0] + ws4[1] + ws4[2] + ws4[3]) / (float)QL_ + 1e-6f);
    bf16* o = out + (long)row * QL_;
    #pragma unroll
    for (int i = 0; i < 6; ++i) {
        int c = threadIdx.x + i * 256;
        o[c] = f2bf(v[i] * rs * ld1(wt, c, f32));
    }
}

// ---------------- kv: rmsnorm(512) + rope(64), in-place safe ----------------
__global__ __launch_bounds__(256) void kv_proc(
    bf16* __restrict__ kvf, const void* __restrict__ wt,
    const void* __restrict__ fcos, const void* __restrict__ fsin,
    const int* __restrict__ gf)
{
    const bool f32 = (*gf == 0);
    int row = blockIdx.x;             // b*2048 + s
    int s = row & (S_ - 1);
    bf16* x = kvf + (long)row * DQK_;
    float v[2]; float ss = 0.f;
    #pragma unroll
    for (int i = 0; i < 2; ++i) { v[i] = bf2f(x[threadIdx.x + i * 256]); ss += v[i] * v[i]; }
    #pragma unroll
    for (int off = 1; off < 64; off <<= 1) ss += __shfl_xor(ss, off);
    __shared__ float ws4[4];
    if ((threadIdx.x & 63) == 0) ws4[threadIdx.x >> 6] = ss;
    __syncthreads();
    float rs = rsqrtf((ws4[0] + ws4[1] + ws4[2] + ws4[3]) / (float)KVL_ + 1e-6f);
    #pragma unroll
    for (int i = 0; i < 2; ++i) {
        int c = threadIdx.x + i * 256;
        x[c] = f2bf(v[i] * rs * ld1(wt, c, f32));
    }
    if (threadIdx.x < 32) {
        int i = threadIdx.x;
        float x0 = bf2f(x[KVL_ + 2 * i]), x1 = bf2f(x[KVL_ + 2 * i + 1]);
        float c = ld1(fcos, s * 32 + i, f32), sn = ld1(fsin, s * 32 + i, f32);
        x[KVL_ + 2 * i]     = f2bf(x0 * c - x1 * sn);
        x[KVL_ + 2 * i + 1] = f2bf(x0 * sn + x1 * c);
    }
}

// ---------------- q pack: qfull (4096,3072) -> qnope (H,4096,128) + roped qpe (H*B,S,64) ----
__global__ __launch_bounds__(512) void q_pack(
    const bf16* __restrict__ qfull, const void* __restrict__ fcos, const void* __restrict__ fsin,
    bf16* __restrict__ qnope, bf16* __restrict__ qpe, const int* __restrict__ gf)
{
    const bool f32 = (*gf == 0);
    int row = blockIdx.x;             // b*2048 + s
    int s = row & (S_ - 1);
    int b = row >> 11;
    const bf16* q = qfull + (long)row * (H_ * QKH_);
    int t = threadIdx.x;
    {   // rope: h = t>>5, i = t&31
        int h = t >> 5, i = t & 31;
        float x0 = bf2f(q[h * QKH_ + NOPE_ + 2 * i]);
        float x1 = bf2f(q[h * QKH_ + NOPE_ + 2 * i + 1]);
        float c = ld1(fcos, s * 32 + i, f32), sn = ld1(fsin, s * 32 + i, f32);
        bf16* dst = qpe + ((long)(h * B_ + b) * S_ + s) * ROPE_;
        dst[2 * i]     = f2bf(x0 * c - x1 * sn);
        dst[2 * i + 1] = f2bf(x0 * sn + x1 * c);
    }
    if (t < 256) {  // nope copy
        int h = t >> 4, d0 = (t & 15) * 8;
        v8s v = *reinterpret_cast<const v8s*>(q + h * QKH_ + d0);
        *reinterpret_cast<v8s*>(qnope + ((long)h * 4096 + row) * NOPE_ + d0) = v;
    }
}

// ---------------- V transpose: kvf[:, :512] -> Vt (B, 512, S) ----------------
__global__ __launch_bounds__(256) void v_transpose(
    const bf16* __restrict__ kcomb, bf16* __restrict__ vt)
{
    __shared__ bf16 tile[64][72];
    int b = blockIdx.z, t0 = blockIdx.x * 64, c0 = blockIdx.y * 64;
    int tid = threadIdx.x;
    int r = tid >> 2, sg = tid & 3;
    const bf16* src = kcomb + ((long)b * S_ + t0 + r) * DQK_ + c0 + sg * 16;
    #pragma unroll
    for (int i = 0; i < 2; ++i)
        *reinterpret_cast<v8s*>(&tile[r][sg * 16 + i * 8]) = reinterpret_cast<const v8s*>(src)[i];
    __syncthreads();
    int c = tid >> 2;
    bf16* dst = vt + ((long)b * KVL_ + c0 + c) * S_ + t0 + sg * 16;
    bf16 tmp[16];
    #pragma unroll
    for (int i = 0; i < 16; ++i) tmp[i] = tile[sg * 16 + i][c];
    #pragma unroll
    for (int i = 0; i < 2; ++i)
        reinterpret_cast<v8s*>(dst)[i] = *reinterpret_cast<v8s*>(&tmp[i * 8]);
}

// ---------------- wkv_b nope rows transpose: (H,128,512) -> wkvbt (H,512,128) ----------------
__global__ __launch_bounds__(256) void wkvb_t_kernel(
    const void* __restrict__ wkvb, bf16* __restrict__ outp, const int* __restrict__ gf)
{
    const bool f32 = (*gf == 0);
    long idx = (long)blockIdx.x * 256 + threadIdx.x;  // 16*512*128
    int h = (int)(idx >> 16);
    int rem = (int)(idx & 65535);
    int c = rem >> 7, d = rem & 127;
    outp[idx] = f2bf(ld1(wkvb, ((long)(h * 256 + d)) * KVL_ + c, f32));
}

// ---------------- flash attention + on-the-fly q_abs + fused output projection ----------------
// Per block: 64 q-rows, one (h,b). Prologue computes qreg = [qnope@wkvbt_h^T | qpe] (A-frag),
// main loop: QK^T(576) -> online softmax -> PV(512), epilogue: out_h = (o/l) @ wv_h^T.
// Main loop uses ping-pong LDS buffers (bufA @0, bufB @9216) + register prefetch:
// one barrier per staged chunk (9 K + 1 + 4 V = 14/kb-iter vs 26 single-buffered).
// LDS (bf16 elems, total 26112 = 52.2 KB):
//   prologue: Qs @0 (64x136), Qn @8704 (64x136), Wt @17408 (64x136)
//   main:     bufA @0 (<=9216), bufB @9216 (<=9216), Ps @18432 (4 x 16x72)
//   epilogue: Po @0 (64x264=16896), Wvs @16896 (128x40=5120)
__global__ __launch_bounds__(256, 2) void attn(
    const bf16* __restrict__ qnope, // (H, 4096, 128)
    const bf16* __restrict__ qpe,   // (H*B, S, 64)
    const bf16* __restrict__ kc,    // (B, S, 576)
    const bf16* __restrict__ vt,    // (B, 512, S)
    const bf16* __restrict__ wkvbt, // (H, 512, 128)
    const void* __restrict__ wkvb,  // external (H*256, 512); rows h*256+128.. = wv
    bf16* __restrict__ oheads,      // (4096, 2048), head h at cols h*128..
    const int* __restrict__ gf)
{
    __shared__ bf16 sm[26112];
    const bool e32 = (*gf == 0);
    const int tid = threadIdx.x;
    const int w = tid >> 6, lane = tid & 63, quad = lane >> 4, l15 = lane & 15;
    const int qb = gridDim.x - 1 - blockIdx.x;   // longest blocks first
    const int bh = blockIdx.y;                    // h*B + b
    const int b = bh & (B_ - 1), h = bh >> 1;
    const int q0 = qb * 64;

    // ---- prologue: stage qnope tile once
    {
        #pragma unroll
        for (int i = 0; i < 4; ++i) {
            int a = tid + i * 256, rr = a >> 4, sg = a & 15;
            *reinterpret_cast<v8s*>(&sm[8704 + rr * 136 + sg * 8]) =
                *reinterpret_cast<const v8s*>(qnope + ((long)h * 4096 + b * 2048 + q0 + rr) * NOPE_ + sg * 8);
        }
    }
    v8s qreg[18];
    // 4 passes x 128 cols of q_abs = qnope_tile @ wkvbt_h^T
    for (int p = 0; p < 4; ++p) {
        for (int nb = 0; nb < 2; ++nb) {
            __syncthreads();
            #pragma unroll
            for (int i = 0; i < 4; ++i) {   // stage Wt: 64 rows (c-dim) x 128 (d-dim)
                int a = tid + i * 256, rr = a >> 4, sg = a & 15;
                *reinterpret_cast<v8s*>(&sm[17408 + rr * 136 + sg * 8]) =
                    *reinterpret_cast<const v8s*>(wkvbt + ((long)h * 512 + p * 128 + nb * 64 + rr) * NOPE_ + sg * 8);
            }
            __syncthreads();
            v4f qacc[4];
            #pragma unroll
            for (int i = 0; i < 4; ++i) qacc[i] = vzero();
            #pragma unroll
            for (int kk = 0; kk < 4; ++kk) {
                v8s aq = *reinterpret_cast<const v8s*>(&sm[8704 + (w * 16 + l15) * 136 + kk * 32 + quad * 8]);
                #pragma unroll
                for (int nt = 0; nt < 4; ++nt) {
                    v8s bw = *reinterpret_cast<const v8s*>(&sm[17408 + (nt * 16 + l15) * 136 + kk * 32 + quad * 8]);
                    qacc[nt] = mfma16(aq, bw, qacc[nt]);
                }
            }
            #pragma unroll
            for (int nt = 0; nt < 4; ++nt)
                #pragma unroll
                for (int r = 0; r < 4; ++r)
                    sm[(w * 16 + quad * 4 + r) * 136 + nb * 64 + nt * 16 + l15] = f2bf(qacc[nt][r]);
        }
        // extract this pass's A-fragments (wave-private rows)
        #pragma unroll
        for (int c2 = 0; c2 < 2; ++c2)
            #pragma unroll
            for (int ks = 0; ks < 2; ++ks)
                qreg[p * 4 + c2 * 2 + ks] =
                    *reinterpret_cast<const v8s*>(&sm[(w * 16 + l15) * 136 + c2 * 64 + ks * 32 + quad * 8]);
    }
    {   // qpe fragments
        const bf16* qp = qpe + ((long)bh * S_ + q0 + w * 16 + l15) * ROPE_;
        qreg[16] = *reinterpret_cast<const v8s*>(qp + quad * 8);
        qreg[17] = *reinterpret_cast<const v8s*>(qp + 32 + quad * 8);
    }
    __syncthreads();   // prologue LDS reads done before main staging overwrites

    const bf16* Kb = kc + (long)b * S_ * DQK_;
    const bf16* Vb = vt + (long)b * KVL_ * S_;
    bf16* Ps  = sm + 18432 + w * 1152;
    const int rr0 = tid >> 3, sg0 = (tid & 7) * 8;   // staging coords (i-th chunk: row rr0+i*32)

    float m_run[4], l_run[4];
    v4f o[32];
    #pragma unroll
    for (int i = 0; i < 32; ++i) o[i] = vzero();
    #pragma unroll
    for (int r = 0; r < 4; ++r) { m_run[r] = -3e38f; l_run[r] = 0.f; }

    for (int kb = 0; kb <= qb; ++kb) {
        const int t0 = kb * 64;
        v4f sacc[4];
        #pragma unroll
        for (int i = 0; i < 4; ++i) sacc[i] = vzero();

        // ---- scores: 9 chunks of 64 d-cols, ping-pong + register prefetch
        v8s pk0 = *reinterpret_cast<const v8s*>(Kb + (long)(t0 + rr0) * DQK_ + sg0);
        v8s pk1 = *reinterpret_cast<const v8s*>(Kb + (long)(t0 + rr0 + 32) * DQK_ + sg0);
        for (int c = 0; c < 9; ++c) {
            bf16* buf = sm + (c & 1) * 9216;
            *reinterpret_cast<v8s*>(buf + rr0 * 72 + sg0) = pk0;
            *reinterpret_cast<v8s*>(buf + (rr0 + 32) * 72 + sg0) = pk1;
            if (c < 8) {
                pk0 = *reinterpret_cast<const v8s*>(Kb + (long)(t0 + rr0) * DQK_ + (c + 1) * 64 + sg0);
                pk1 = *reinterpret_cast<const v8s*>(Kb + (long)(t0 + rr0 + 32) * DQK_ + (c + 1) * 64 + sg0);
            }
            __syncthreads();
            #pragma unroll
            for (int ks = 0; ks < 2; ++ks) {
                v8s aq = qreg[c * 2 + ks];
                #pragma unroll
                for (int nt = 0; nt < 4; ++nt) {
                    v8s bk = *reinterpret_cast<const v8s*>(buf + (nt * 16 + l15) * 72 + ks * 32 + quad * 8);
                    sacc[nt] = mfma16(aq, bk, sacc[nt]);
                }
            }
        }

        // ---- prefetch V chunk 0 (latency hides under softmax)
        v8s pv0 = *reinterpret_cast<const v8s*>(Vb + (long)(rr0      ) * S_ + t0 + sg0);
        v8s pv1 = *reinterpret_cast<const v8s*>(Vb + (long)(rr0 +  32) * S_ + t0 + sg0);
        v8s pv2 = *reinterpret_cast<const v8s*>(Vb + (long)(rr0 +  64) * S_ + t0 + sg0);
        v8s pv3 = *reinterpret_cast<const v8s*>(Vb + (long)(rr0 +  96) * S_ + t0 + sg0);

        // ---- scale + causal mask
        #pragma unroll
        for (int nt = 0; nt < 4; ++nt) {
            int col = t0 + nt * 16 + l15;
            #pragma unroll
            for (int r = 0; r < 4; ++r) {
                int row = q0 + w * 16 + quad * 4 + r;
                float s = sacc[nt][r] * SCALE_;
                sacc[nt][r] = (col <= row) ? s : -3e38f;
            }
        }
        // ---- online softmax (state replicated across each quad's 16 lanes)
        float al[4];
        #pragma unroll
        for (int r = 0; r < 4; ++r) {
            float mx = fmaxf(fmaxf(sacc[0][r], sacc[1][r]), fmaxf(sacc[2][r], sacc[3][r]));
            mx = fmaxf(mx, __shfl_xor(mx, 1));
            mx = fmaxf(mx, __shfl_xor(mx, 2));
            mx = fmaxf(mx, __shfl_xor(mx, 4));
            mx = fmaxf(mx, __shfl_xor(mx, 8));
            float mnew = fmaxf(m_run[r], mx);
            al[r] = exp2f((m_run[r] - mnew) * LOG2E);
            m_run[r] = mnew;
        }
        float rsum[4] = {0.f, 0.f, 0.f, 0.f};
        #pragma unroll
        for (int nt = 0; nt < 4; ++nt)
            #pragma unroll
            for (int r = 0; r < 4; ++r) {
                float pv = exp2f((sacc[nt][r] - m_run[r]) * LOG2E);
                rsum[r] += pv;
                Ps[(quad * 4 + r) * 72 + nt * 16 + l15] = f2bf(pv);
            }
        #pragma unroll
        for (int r = 0; r < 4; ++r) {
            float t = rsum[r];
            t += __shfl_xor(t, 1);
            t += __shfl_xor(t, 2);
            t += __shfl_xor(t, 4);
            t += __shfl_xor(t, 8);
            l_run[r] = l_run[r] * al[r] + t;
        }
        #pragma unroll
        for (int i = 0; i < 32; ++i)
            #pragma unroll
            for (int r = 0; r < 4; ++r) o[i][r] *= al[r];

        __syncthreads();   // all waves done with K mfma (bufA) before V staging overwrites

        // ---- PV: 4 chunks of 128 V-rows (ctx cols), ping-pong + prefetch
        for (int vc = 0; vc < 4; ++vc) {
            bf16* buf = sm + (vc & 1) * 9216;
            *reinterpret_cast<v8s*>(buf + (rr0      ) * 72 + sg0) = pv0;
            *reinterpret_cast<v8s*>(buf + (rr0 + 32) * 72 + sg0) = pv1;
            *reinterpret_cast<v8s*>(buf + (rr0 + 64) * 72 + sg0) = pv2;
            *reinterpret_cast<v8s*>(buf + (rr0 + 96) * 72 + sg0) = pv3;
            if (vc < 3) {
                pv0 = *reinterpret_cast<const v8s*>(Vb + (long)((vc + 1) * 128 + rr0      ) * S_ + t0 + sg0);
                pv1 = *reinterpret_cast<const v8s*>(Vb + (long)((vc + 1) * 128 + rr0 + 32) * S_ + t0 + sg0);
                pv2 = *reinterpret_cast<const v8s*>(Vb + (long)((vc + 1) * 128 + rr0 + 64) * S_ + t0 + sg0);
                pv3 = *reinterpret_cast<const v8s*>(Vb + (long)((vc + 1) * 128 + rr0 + 96) * S_ + t0 + sg0);
            }
            __syncthreads();
            #pragma unroll
            for (int ks = 0; ks < 2; ++ks) {
                v8s pa = *reinterpret_cast<const v8s*>(Ps + l15 * 72 + ks * 32 + quad * 8);
                #pragma unroll
                for (int nt = 0; nt < 8; ++nt) {
                    v8s bv = *reinterpret_cast<const v8s*>(buf + (nt * 16 + l15) * 72 + ks * 32 + quad * 8);
                    o[vc * 8 + nt] = mfma16(pa, bv, o[vc * 8 + nt]);
                }
            }
        }
    }

    // ---- fused epilogue: out_h = (o/l) @ wv_h^T, K=512 in 2x8 chunks
    __syncthreads();
    float inv[4];
    #pragma unroll
    for (int r = 0; r < 4; ++r) inv[r] = 1.0f / l_run[r];
    bf16* Po  = sm;            // [64][264], wave w owns rows w*16..+15
    bf16* Wvs = sm + 16896;    // [128][40]
    v4f oacc[8];
    #pragma unroll
    for (int i = 0; i < 8; ++i) oacc[i] = vzero();

    for (int Hh = 0; Hh < 2; ++Hh) {
        #pragma unroll
        for (int i = 0; i < 16; ++i) {
            int ii = Hh * 16 + i;
            #pragma unroll
            for (int r = 0; r < 4; ++r)
                Po[(w * 16 + quad * 4 + r) * 264 + i * 16 + l15] = f2bf(o[ii][r] * inv[r]);
        }
        for (int kcc = 0; kcc < 8; ++kcc) {
            __syncthreads();
            #pragma unroll
            for (int i = 0; i < 2; ++i) {
                int a = tid + i * 256, rr = a >> 2, sg = a & 3;
                *reinterpret_cast<v8s*>(Wvs + rr * 40 + sg * 8) =
                    ld8(wkvb, (long)(h * 256 + 128 + rr) * KVL_ + Hh * 256 + kcc * 32 + sg * 8, e32);
            }
            __syncthreads();
            v8s aq = *reinterpret_cast<const v8s*>(Po + (w * 16 + l15) * 264 + kcc * 32 + quad * 8);
            #pragma unroll
            for (int nt = 0; nt < 8; ++nt) {
                v8s bw = *reinterpret_cast<const v8s*>(Wvs + (nt * 16 + l15) * 40 + quad * 8);
                oacc[nt] = mfma16(aq, bw, oacc[nt]);
            }
        }
    }
    #pragma unroll
    for (int nt = 0; nt < 8; ++nt)
        #pragma unroll
        for (int r = 0; r < 4; ++r)
            oheads[(long)(b * S_ + q0 + w * 16 + quad * 4 + r) * 2048 + h * 128 + nt * 16 + l15] = f2bf(oacc[nt][r]);
}

extern "C" void kernel_launch(void* const* d_in, const int* in_sizes, int n_in,
                              void* d_out, int out_size, void* d_ws, size_t ws_size,
                              hipStream_t stream) {
    const void* x     = d_in[0];
    const void* fcos  = d_in[1];
    const void* fsin  = d_in[2];
    // d_in[3] = mask (causal) — implemented directly
    const void* wq_a  = d_in[4];
    const void* q_ln  = d_in[5];
    const void* wq_b  = d_in[6];
    const void* wkv_a = d_in[7];
    const void* kv_ln = d_in[8];
    const void* wkv_b = d_in[9];
    const void* wo    = d_in[10];

    // workspace (bf16 elems), peak 30,670,864 elems ~= 58.5 MiB
    bf16* W = (bf16*)d_ws;
    bf16* t0     = W;                 // 6,291,456 (dead after GEMM2)
    bf16* qnope  = W;                 // 8,388,608 (written by q_pack, after t0 dead)
    bf16* qpe    = W + 8388608L;      // 4,194,304
    bf16* qfull  = W + 12582912L;     // 12,582,912 (dead after q_pack)
    bf16* oheads = W + 12582912L;     // 8,388,608 (over qfull)
    bf16* kvf    = W + 25165824L;     // 2,359,296
    bf16* vtb    = W + 27525120L;     // 2,097,152
    bf16* wkvbt  = W + 29622272L;     // 1,048,576
    int*  gflag  = (int*)(W + 30670848L);

    detect_k<<<dim3(1), dim3(64), 0, stream>>>((const unsigned*)fcos, gflag);
    wkvb_t_kernel<<<dim3(4096), dim3(256), 0, stream>>>(wkv_b, wkvbt, gflag);

    // GEMM1: t0 = x @ wq_a^T   (4096 x 1536 x 2048)
    gemm_bt<<<dim3(24, 64, 1), dim3(256), 0, stream>>>(
        x, 2048L, 0L, 1, wq_a, 2048L, 0L, 1, t0, 1536L, 0L, 0, 2048, gflag);
    rmsnorm_q<<<dim3(4096), dim3(256), 0, stream>>>(t0, q_ln, t0, gflag);

    // GEMM2: qfull = t0 @ wq_b^T  (4096 x 3072 x 1536)
    gemm_bt<<<dim3(48, 64, 1), dim3(256), 0, stream>>>(
        t0, 1536L, 0L, 0, wq_b, 1536L, 0L, 1, qfull, 3072L, 0L, 0, 1536, gflag);

    // GEMM3: kvf = x @ wkv_a^T  (4096 x 576 x 2048)
    gemm_bt<<<dim3(9, 64, 1), dim3(256), 0, stream>>>(
        x, 2048L, 0L, 1, wkv_a, 2048L, 0L, 1, kvf, 576L, 0L, 0, 2048, gflag);

    q_pack<<<dim3(4096), dim3(512), 0, stream>>>(qfull, fcos, fsin, qnope, qpe, gflag);
    kv_proc<<<dim3(4096), dim3(256), 0, stream>>>(kvf, kv_ln, fcos, fsin, gflag);
    v_transpose<<<dim3(32, 8, 2), dim3(256), 0, stream>>>(kvf, vtb);

    // attention (+ on-the-fly q_abs, + fused per-head out projection) -> oheads
    attn<<<dim3(32, 32), dim3(256), 0, stream>>>(
        qnope, qpe, kvf, vtb, wkvbt, wkv_b, oheads, gflag);

    // GEMM7: out = oheads @ wo^T  (4096 x 2048 x 2048), out dtype per flag
    gemm_bt<<<dim3(32, 64, 1), dim3(256), 0, stream>>>(
        oheads, 2048L, 0L, 0, wo, 2048L, 0L, 1, d_out, 2048L, 0L, 1, 2048, gflag);
}